// Round 1
// baseline (3994.164 us; speedup 1.0000x reference)
//
#include <hip/hip_runtime.h>
#include <hip/hip_bf16.h>
#include <math.h>

#define BATCH 4
#define SEQ   2048
#define EMB   1024
#define NH    16
#define DKS   64

// ---------------------------------------------------------------------------
// Generic tiled fp32 GEMM: C = A(MxK) * B(KxN), all row-major.
// Batched via grid.z: A += (z/hdiv)*aStride, B += (z%hdiv)*bStride, C += z*cStride.
// Tile 64x64, K-chunk 32, 256 threads, 4x4 micro-tile per thread.
// A tile stored TRANSPOSED in LDS ([k][m]) so both fragments load as float4.
// ---------------------------------------------------------------------------
__global__ __launch_bounds__(256) void gemm_tiled_f32(
    const float* __restrict__ A, const float* __restrict__ Bw, float* __restrict__ C,
    int M, int N, int K, int hdiv, long aStride, long bStride, long cStride)
{
    __shared__ float As[32][68];  // [k][m], pad 64->68 keeps 16B alignment per row
    __shared__ float Bs[32][68];  // [k][n]

    const int z = blockIdx.z;
    A  += (long)(z / hdiv) * aStride;
    Bw += (long)(z % hdiv) * bStride;
    C  += (long)z * cStride;

    const int m0 = blockIdx.x * 64;
    const int n0 = blockIdx.y * 64;
    const int t  = threadIdx.x;
    const int tx = t & 15;        // 0..15 -> 4 output cols
    const int ty = t >> 4;        // 0..15 -> 4 output rows

    float acc[4][4] = {{0.f}};

    for (int k0 = 0; k0 < K; k0 += 32) {
        // stage A tile (64 rows x 32 k) transposed into As[k][m]
        #pragma unroll
        for (int i = 0; i < 2; ++i) {
            int idx = t + i * 256;            // 0..511 float4s
            int r   = idx >> 3;               // m row 0..63
            int c4  = idx & 7;                // k group 0..7
            const float4 v = *(const float4*)(A + (long)(m0 + r) * K + k0 + c4 * 4);
            As[c4 * 4 + 0][r] = v.x;
            As[c4 * 4 + 1][r] = v.y;
            As[c4 * 4 + 2][r] = v.z;
            As[c4 * 4 + 3][r] = v.w;
        }
        // stage B tile (32 k x 64 n)
        #pragma unroll
        for (int i = 0; i < 2; ++i) {
            int idx = t + i * 256;
            int r   = idx >> 4;               // k row 0..31
            int c4  = idx & 15;               // n group 0..15
            *(float4*)&Bs[r][c4 * 4] = *(const float4*)(Bw + (long)(k0 + r) * N + n0 + c4 * 4);
        }
        __syncthreads();

        #pragma unroll
        for (int kk = 0; kk < 32; ++kk) {
            const float4 av = *(const float4*)&As[kk][ty * 4];
            const float4 bv = *(const float4*)&Bs[kk][tx * 4];
            const float a4[4] = {av.x, av.y, av.z, av.w};
            const float b4[4] = {bv.x, bv.y, bv.z, bv.w};
            #pragma unroll
            for (int i = 0; i < 4; ++i)
                #pragma unroll
                for (int j = 0; j < 4; ++j)
                    acc[i][j] = fmaf(a4[i], b4[j], acc[i][j]);
        }
        __syncthreads();
    }

    #pragma unroll
    for (int i = 0; i < 4; ++i) {
        float4 v = make_float4(acc[i][0], acc[i][1], acc[i][2], acc[i][3]);
        *(float4*)(C + (long)(m0 + ty * 4 + i) * N + n0 + tx * 4) = v;
    }
}

// ---------------------------------------------------------------------------
// Flash attention fp32, one wave per 64 q-rows, lane = one q-row.
// K/V rows are read at wave-uniform addresses -> scalar (s_load) path, no LDS.
// Online softmax per lane. scores = (q.k) * 8  (reference divides by sqrt(1/dk)).
// Output written in [b, s, h, dk] layout so the reshape before w_o is free.
// ---------------------------------------------------------------------------
__global__ __launch_bounds__(64) void flash_attn_f32(
    const float* __restrict__ Qm, const float* __restrict__ Km,
    const float* __restrict__ Vm, float* __restrict__ Om,
    const int* __restrict__ maskp)
{
    const int qt   = blockIdx.x;
    const int h    = blockIdx.y;
    const int b    = blockIdx.z;
    const int lane = threadIdx.x;
    const int q0   = qt * 64;
    const int qr   = q0 + lane;
    const int masking = maskp[0];

    const long bh = (long)b * NH + h;
    const float* __restrict__ Kb = Km + bh * SEQ * DKS;
    const float* __restrict__ Vb = Vm + bh * SEQ * DKS;

    float4 q[16], o[16];
    {
        const float* qrow = Qm + (bh * SEQ + qr) * DKS;
        #pragma unroll
        for (int i = 0; i < 16; ++i) q[i] = *(const float4*)(qrow + i * 4);
    }
    #pragma unroll
    for (int i = 0; i < 16; ++i) o[i] = make_float4(0.f, 0.f, 0.f, 0.f);

    float m = -INFINITY, l = 0.f;

    const int ncol = masking ? (q0 + 64) : SEQ;
    for (int c0 = 0; c0 < ncol; c0 += 16) {
        if (masking && c0 > qr) break;   // this lane is fully past the diagonal

        float s[16];
        #pragma unroll
        for (int j = 0; j < 16; ++j) {
            const float* kr = Kb + (long)(c0 + j) * DKS;   // wave-uniform address
            float acc = 0.f;
            #pragma unroll
            for (int d4 = 0; d4 < 16; ++d4) {
                const float4 kv = *(const float4*)(kr + d4 * 4);
                acc = fmaf(q[d4].x, kv.x, acc);
                acc = fmaf(q[d4].y, kv.y, acc);
                acc = fmaf(q[d4].z, kv.z, acc);
                acc = fmaf(q[d4].w, kv.w, acc);
            }
            s[j] = acc * 8.0f;
            if (masking && (c0 + j > qr)) s[j] = -INFINITY;
        }

        float cmax = s[0];
        #pragma unroll
        for (int j = 1; j < 16; ++j) cmax = fmaxf(cmax, s[j]);

        if (cmax > m) {                       // rescale only when max grows
            const float alpha = __expf(m - cmax);   // m=-inf -> alpha=0 (o is 0 anyway)
            m = cmax;
            l *= alpha;
            #pragma unroll
            for (int i = 0; i < 16; ++i) {
                o[i].x *= alpha; o[i].y *= alpha; o[i].z *= alpha; o[i].w *= alpha;
            }
        }

        #pragma unroll
        for (int j = 0; j < 16; ++j) {
            const float p = __expf(s[j] - m);   // masked: exp(-inf - finite) = 0
            l += p;
            const float* vr = Vb + (long)(c0 + j) * DKS;  // wave-uniform address
            #pragma unroll
            for (int d4 = 0; d4 < 16; ++d4) {
                const float4 vv = *(const float4*)(vr + d4 * 4);
                o[d4].x = fmaf(p, vv.x, o[d4].x);
                o[d4].y = fmaf(p, vv.y, o[d4].y);
                o[d4].z = fmaf(p, vv.z, o[d4].z);
                o[d4].w = fmaf(p, vv.w, o[d4].w);
            }
        }
    }

    const float inv = 1.0f / l;
    float* orow = Om + ((long)(b * SEQ + qr)) * EMB + h * DKS;  // [b,s,h,dk]
    #pragma unroll
    for (int i = 0; i < 16; ++i) {
        float4 v = make_float4(o[i].x * inv, o[i].y * inv, o[i].z * inv, o[i].w * inv);
        *(float4*)(orow + i * 4) = v;
    }
}

// ---------------------------------------------------------------------------
extern "C" void kernel_launch(void* const* d_in, const int* in_sizes, int n_in,
                              void* d_out, int out_size, void* d_ws, size_t ws_size,
                              hipStream_t stream)
{
    const float* x_q = (const float*)d_in[0];
    const float* x_k = (const float*)d_in[1];
    const float* x_v = (const float*)d_in[2];
    const float* w_q = (const float*)d_in[3];
    const float* w_k = (const float*)d_in[4];
    const float* w_v = (const float*)d_in[5];
    const float* w_o = (const float*)d_in[6];
    const int*  maskp = (const int*)d_in[7];
    float* out = (float*)d_out;
    float* ws  = (float*)d_ws;

    // workspace layout (floats): Q | K | V | attn  (each B*H*S*DK = 8388608)
    float* Q    = ws;
    float* K    = ws + (size_t)8388608;
    float* V    = ws + (size_t)16777216;
    float* attn = ws + (size_t)25165824;   // [b, s, h*dk] for the out-proj

    const dim3 blk(256);

    // QKV projections: per (b,h): x[b](S x E) * w[h](E x DK) -> (S x DK)
    const dim3 gp(SEQ / 64, DKS / 64, BATCH * NH);
    gemm_tiled_f32<<<gp, blk, 0, stream>>>(x_q, w_q, Q, SEQ, DKS, EMB, NH,
        (long)SEQ * EMB, (long)EMB * DKS, (long)SEQ * DKS);
    gemm_tiled_f32<<<gp, blk, 0, stream>>>(x_k, w_k, K, SEQ, DKS, EMB, NH,
        (long)SEQ * EMB, (long)EMB * DKS, (long)SEQ * DKS);
    gemm_tiled_f32<<<gp, blk, 0, stream>>>(x_v, w_v, V, SEQ, DKS, EMB, NH,
        (long)SEQ * EMB, (long)EMB * DKS, (long)SEQ * DKS);

    // attention
    const dim3 gf(SEQ / 64, NH, BATCH);
    flash_attn_f32<<<gf, dim3(64), 0, stream>>>(Q, K, V, attn, maskp);

    // output projection: attn(B*S x E) * w_o(E x E) -> out
    const dim3 go((BATCH * SEQ) / 64, EMB / 64, 1);
    gemm_tiled_f32<<<go, blk, 0, stream>>>(attn, w_o, out, BATCH * SEQ, EMB, EMB, 1,
        0L, 0L, 0L);
}

// Round 3
// 1918.858 us; speedup vs baseline: 2.0815x; 2.0815x over previous
//
#include <hip/hip_runtime.h>
#include <hip/hip_bf16.h>
#include <math.h>

#define BATCH 4
#define SEQ   2048
#define EMB   1024
#define NH    16
#define DKS   64

typedef __attribute__((ext_vector_type(8))) short short8v;   // 8 bf16 (4 VGPRs)
typedef __attribute__((ext_vector_type(4))) float f32x4;
typedef __attribute__((ext_vector_type(4))) unsigned short u16x4;
typedef unsigned short u16;

#define MFMA(a, b, c) __builtin_amdgcn_mfma_f32_16x16x32_bf16((a), (b), (c), 0, 0, 0)

__device__ __forceinline__ u16 f2bf(float x) {
    __hip_bfloat16 h = __float2bfloat16(x);            // RTN
    return __builtin_bit_cast(u16, h);
}
__device__ __forceinline__ float bf2f(u16 u) {
    unsigned v = ((unsigned)u) << 16;
    return __builtin_bit_cast(float, v);
}

// ---------------------------------------------------------------------------
// Tiled fp32 GEMM: C = A(MxK) * B(KxN), row-major. Batched via grid.z.
// mode 0: fp32 C.  mode 1: bf16 hi/lo planes, row-major [M][N], pre-scaled.
// mode 2: bf16 hi/lo planes TRANSPOSED [N][M] (for V^T), pre-scaled.
// ---------------------------------------------------------------------------
__global__ __launch_bounds__(256) void gemm_tiled_f32(
    const float* __restrict__ A, const float* __restrict__ Bw,
    float* __restrict__ C, u16* __restrict__ Chi, u16* __restrict__ Clo,
    int M, int N, int K, int hdiv, long aStride, long bStride, long cStride,
    int mode, float scale)
{
    __shared__ float As[32][68];  // [k][m]
    __shared__ float Bs[32][68];  // [k][n]

    const int z = blockIdx.z;
    A  += (long)(z / hdiv) * aStride;
    Bw += (long)(z % hdiv) * bStride;
    if (mode == 0) C += (long)z * cStride;
    else { Chi += (long)z * cStride; Clo += (long)z * cStride; }

    const int m0 = blockIdx.x * 64;
    const int n0 = blockIdx.y * 64;
    const int t  = threadIdx.x;
    const int tx = t & 15;
    const int ty = t >> 4;

    float acc[4][4] = {{0.f}};

    for (int k0 = 0; k0 < K; k0 += 32) {
        #pragma unroll
        for (int i = 0; i < 2; ++i) {
            int idx = t + i * 256;
            int r   = idx >> 3;
            int c4  = idx & 7;
            const float4 v = *(const float4*)(A + (long)(m0 + r) * K + k0 + c4 * 4);
            As[c4 * 4 + 0][r] = v.x;
            As[c4 * 4 + 1][r] = v.y;
            As[c4 * 4 + 2][r] = v.z;
            As[c4 * 4 + 3][r] = v.w;
        }
        #pragma unroll
        for (int i = 0; i < 2; ++i) {
            int idx = t + i * 256;
            int r   = idx >> 4;
            int c4  = idx & 15;
            *(float4*)&Bs[r][c4 * 4] = *(const float4*)(Bw + (long)(k0 + r) * N + n0 + c4 * 4);
        }
        __syncthreads();

        #pragma unroll
        for (int kk = 0; kk < 32; ++kk) {
            const float4 av = *(const float4*)&As[kk][ty * 4];
            const float4 bv = *(const float4*)&Bs[kk][tx * 4];
            const float a4[4] = {av.x, av.y, av.z, av.w};
            const float b4[4] = {bv.x, bv.y, bv.z, bv.w};
            #pragma unroll
            for (int i = 0; i < 4; ++i)
                #pragma unroll
                for (int j = 0; j < 4; ++j)
                    acc[i][j] = fmaf(a4[i], b4[j], acc[i][j]);
        }
        __syncthreads();
    }

    if (mode == 0) {
        #pragma unroll
        for (int i = 0; i < 4; ++i) {
            float4 v = make_float4(acc[i][0], acc[i][1], acc[i][2], acc[i][3]);
            *(float4*)(C + (long)(m0 + ty * 4 + i) * N + n0 + tx * 4) = v;
        }
    } else if (mode == 1) {
        #pragma unroll
        for (int i = 0; i < 4; ++i) {
            const int row = m0 + ty * 4 + i;
            u16x4 hv, lv;
            #pragma unroll
            for (int c = 0; c < 4; ++c) {
                const float x = acc[i][c] * scale;
                const u16 hu = f2bf(x);
                hv[c] = hu;
                lv[c] = f2bf(x - bf2f(hu));
            }
            *(u16x4*)(Chi + (size_t)row * N + n0 + tx * 4) = hv;
            *(u16x4*)(Clo + (size_t)row * N + n0 + tx * 4) = lv;
        }
    } else { // mode 2: transposed [N][M], M == SEQ here
        #pragma unroll
        for (int i = 0; i < 4; ++i) {
            const int row = m0 + ty * 4 + i;
            #pragma unroll
            for (int c = 0; c < 4; ++c) {
                const int col = n0 + tx * 4 + c;
                const float x = acc[i][c] * scale;
                const u16 hu = f2bf(x);
                Chi[(size_t)col * M + row] = hu;
                Clo[(size_t)col * M + row] = f2bf(x - bf2f(hu));
            }
        }
    }
}

// ---------------------------------------------------------------------------
// MFMA flash attention. Block = 256 threads = 4 waves; wave = 16 q-rows.
// 32-key steps: QK^T via bf16 hi/lo split (6 MFMAs per 16-key subtile),
// online softmax in the verified C-layout (row=(l>>4)*4+reg, col=l&15),
// P->bf16 through per-wave LDS, PV with V^T hi/lo (8 MFMAs).
// Q planes are pre-scaled by 8 (reference multiplies scores by sqrt(dk)=8).
// ---------------------------------------------------------------------------
__global__ __launch_bounds__(256) void flash_mfma(
    const u16* __restrict__ Qhi, const u16* __restrict__ Qlo,
    const u16* __restrict__ Khi, const u16* __restrict__ Klo,
    const u16* __restrict__ VThi, const u16* __restrict__ VTlo,
    float* __restrict__ Om, const int* __restrict__ maskp)
{
    const int t   = threadIdx.x;
    const int wv  = t >> 6;
    const int l   = t & 63;
    const int g   = l >> 4;     // lane group 0..3
    const int m16 = l & 15;
    const int h = blockIdx.y, b = blockIdx.z;
    const int q0 = blockIdx.x * 64 + wv * 16;
    const int msk = maskp[0];

    const size_t bh = (size_t)b * NH + h;
    const u16* __restrict__ Qh = Qhi + bh * SEQ * DKS;
    const u16* __restrict__ Ql = Qlo + bh * SEQ * DKS;
    const u16* __restrict__ Kh = Khi + bh * SEQ * DKS;
    const u16* __restrict__ Kl = Klo + bh * SEQ * DKS;
    const u16* __restrict__ Vh = VThi + bh * DKS * SEQ;
    const u16* __restrict__ Vl = VTlo + bh * DKS * SEQ;

    // Q fragments (held for the whole kernel)
    const size_t qoff = (size_t)(q0 + m16) * DKS + 8 * g;
    const short8v qh0 = *(const short8v*)(Qh + qoff);
    const short8v qh1 = *(const short8v*)(Qh + qoff + 32);
    const short8v ql0 = *(const short8v*)(Ql + qoff);
    const short8v ql1 = *(const short8v*)(Ql + qoff + 32);

    f32x4 o0 = {0.f, 0.f, 0.f, 0.f}, o1 = o0, o2 = o0, o3 = o0;
    float mr[4] = {-INFINITY, -INFINITY, -INFINITY, -INFINITY};
    float lr[4] = {0.f, 0.f, 0.f, 0.f};

    __shared__ u16 P_lds[4][16][32];

    const int qrow_base = q0 + 4 * g;          // this lane's C rows: +0..3
    const int ncol = msk ? (q0 + 16) : SEQ;

    for (int k0 = 0; k0 < ncol; k0 += 32) {
        f32x4 s0 = {0.f, 0.f, 0.f, 0.f}, s1 = s0;
        {
            const size_t ko = (size_t)(k0 + m16) * DKS + 8 * g;
            const short8v kh0 = *(const short8v*)(Kh + ko);
            const short8v kh1 = *(const short8v*)(Kh + ko + 32);
            const short8v kl0 = *(const short8v*)(Kl + ko);
            const short8v kl1 = *(const short8v*)(Kl + ko + 32);
            s0 = MFMA(qh0, kh0, s0); s0 = MFMA(qh1, kh1, s0);
            s0 = MFMA(ql0, kh0, s0); s0 = MFMA(ql1, kh1, s0);
            s0 = MFMA(qh0, kl0, s0); s0 = MFMA(qh1, kl1, s0);
        }
        {
            const size_t ko = (size_t)(k0 + 16 + m16) * DKS + 8 * g;
            const short8v kh0 = *(const short8v*)(Kh + ko);
            const short8v kh1 = *(const short8v*)(Kh + ko + 32);
            const short8v kl0 = *(const short8v*)(Kl + ko);
            const short8v kl1 = *(const short8v*)(Kl + ko + 32);
            s1 = MFMA(qh0, kh0, s1); s1 = MFMA(qh1, kh1, s1);
            s1 = MFMA(ql0, kh0, s1); s1 = MFMA(ql1, kh1, s1);
            s1 = MFMA(qh0, kl0, s1); s1 = MFMA(qh1, kl1, s1);
        }

        if (msk && (k0 + 31 > q0)) {           // diagonal-straddling tiles only
            #pragma unroll
            for (int r = 0; r < 4; ++r) {
                if (k0 + m16      > qrow_base + r) s0[r] = -INFINITY;
                if (k0 + 16 + m16 > qrow_base + r) s1[r] = -INFINITY;
            }
        }

        float al[4];
        #pragma unroll
        for (int r = 0; r < 4; ++r) {
            float v = fmaxf(s0[r], s1[r]);
            v = fmaxf(v, __shfl_xor(v, 1));
            v = fmaxf(v, __shfl_xor(v, 2));
            v = fmaxf(v, __shfl_xor(v, 4));
            v = fmaxf(v, __shfl_xor(v, 8));
            const float mn = fmaxf(mr[r], v);  // v is always finite (k0 <= q-rows)
            al[r] = __expf(mr[r] - mn);        // first tile: exp(-inf)=0
            mr[r] = mn;
        }
        #pragma unroll
        for (int r = 0; r < 4; ++r) {
            const u16 up0 = f2bf(__expf(s0[r] - mr[r]));
            const u16 up1 = f2bf(__expf(s1[r] - mr[r]));
            lr[r] = lr[r] * al[r] + bf2f(up0) + bf2f(up1);  // denom matches bf16 P
            P_lds[wv][4 * g + r][m16]      = up0;
            P_lds[wv][4 * g + r][16 + m16] = up1;
            o0[r] *= al[r]; o1[r] *= al[r]; o2[r] *= al[r]; o3[r] *= al[r];
        }

        // A-fragment of P (intra-wave LDS bounce, no barrier needed)
        const short8v pa = *(const short8v*)&P_lds[wv][m16][8 * g];

        // PV: O += P * (Vhi + Vlo), V^T rows are contiguous in k
        const size_t vo = (size_t)m16 * SEQ + k0 + 8 * g;
        short8v vh, vl;
        vh = *(const short8v*)(Vh + vo);
        vl = *(const short8v*)(Vl + vo);
        o0 = MFMA(pa, vh, o0); o0 = MFMA(pa, vl, o0);
        vh = *(const short8v*)(Vh + vo + 16 * SEQ);
        vl = *(const short8v*)(Vl + vo + 16 * SEQ);
        o1 = MFMA(pa, vh, o1); o1 = MFMA(pa, vl, o1);
        vh = *(const short8v*)(Vh + vo + 32 * SEQ);
        vl = *(const short8v*)(Vl + vo + 32 * SEQ);
        o2 = MFMA(pa, vh, o2); o2 = MFMA(pa, vl, o2);
        vh = *(const short8v*)(Vh + vo + 48 * SEQ);
        vl = *(const short8v*)(Vl + vo + 48 * SEQ);
        o3 = MFMA(pa, vh, o3); o3 = MFMA(pa, vl, o3);
    }

    float inv[4];
    #pragma unroll
    for (int r = 0; r < 4; ++r) {
        float v = lr[r];
        v += __shfl_xor(v, 1);
        v += __shfl_xor(v, 2);
        v += __shfl_xor(v, 4);
        v += __shfl_xor(v, 8);
        inv[r] = 1.0f / v;
    }
    #pragma unroll
    for (int r = 0; r < 4; ++r) {
        const size_t obase = ((size_t)b * SEQ + qrow_base + r) * EMB + h * DKS + m16;
        Om[obase +  0] = o0[r] * inv[r];
        Om[obase + 16] = o1[r] * inv[r];
        Om[obase + 32] = o2[r] * inv[r];
        Om[obase + 48] = o3[r] * inv[r];
    }
}

// ---------------------------------------------------------------------------
extern "C" void kernel_launch(void* const* d_in, const int* in_sizes, int n_in,
                              void* d_out, int out_size, void* d_ws, size_t ws_size,
                              hipStream_t stream)
{
    const float* x_q = (const float*)d_in[0];
    const float* x_k = (const float*)d_in[1];
    const float* x_v = (const float*)d_in[2];
    const float* w_q = (const float*)d_in[3];
    const float* w_k = (const float*)d_in[4];
    const float* w_v = (const float*)d_in[5];
    const float* w_o = (const float*)d_in[6];
    const int*  maskp = (const int*)d_in[7];
    float* out = (float*)d_out;

    // workspace: 6 bf16 planes (Qhi,Qlo,Khi,Klo,VThi,VTlo; 16 MB each) + attn fp32 (32 MB) = 128 MB
    const size_t PLANE = (size_t)BATCH * NH * SEQ * DKS;   // 8M elements
    u16* Qhi  = (u16*)d_ws;
    u16* Qlo  = Qhi + PLANE;
    u16* Khi  = Qhi + 2 * PLANE;
    u16* Klo  = Qhi + 3 * PLANE;
    u16* VThi = Qhi + 4 * PLANE;
    u16* VTlo = Qhi + 5 * PLANE;
    float* attn = (float*)(Qhi + 6 * PLANE);               // [B][S][H*DK]

    const dim3 blk(256);

    // projections -> bf16 hi/lo planes; Q pre-scaled by 8 (score scale)
    const dim3 gp(SEQ / 64, DKS / 64, BATCH * NH);
    gemm_tiled_f32<<<gp, blk, 0, stream>>>(x_q, w_q, nullptr, Qhi, Qlo, SEQ, DKS, EMB, NH,
        (long)SEQ * EMB, (long)EMB * DKS, (long)SEQ * DKS, 1, 8.0f);
    gemm_tiled_f32<<<gp, blk, 0, stream>>>(x_k, w_k, nullptr, Khi, Klo, SEQ, DKS, EMB, NH,
        (long)SEQ * EMB, (long)EMB * DKS, (long)SEQ * DKS, 1, 1.0f);
    gemm_tiled_f32<<<gp, blk, 0, stream>>>(x_v, w_v, nullptr, VThi, VTlo, SEQ, DKS, EMB, NH,
        (long)SEQ * EMB, (long)EMB * DKS, (long)DKS * SEQ, 2, 1.0f);

    // attention
    const dim3 gf(SEQ / 64, NH, BATCH);
    flash_mfma<<<gf, blk, 0, stream>>>(Qhi, Qlo, Khi, Klo, VThi, VTlo, attn, maskp);

    // output projection (fp32)
    const dim3 go((BATCH * SEQ) / 64, EMB / 64, 1);
    gemm_tiled_f32<<<go, blk, 0, stream>>>(attn, w_o, out, nullptr, nullptr,
        BATCH * SEQ, EMB, EMB, 1, 0L, 0L, 0L, 0, 1.0f);
}

// Round 4
// 1465.259 us; speedup vs baseline: 2.7259x; 1.3096x over previous
//
#include <hip/hip_runtime.h>
#include <hip/hip_bf16.h>
#include <math.h>

#define BATCH 4
#define SEQ   2048
#define EMB   1024
#define NH    16
#define DKS   64

typedef __attribute__((ext_vector_type(8))) short short8v;   // 8 bf16 (4 VGPRs)
typedef __attribute__((ext_vector_type(4))) float f32x4;
typedef __attribute__((ext_vector_type(4))) unsigned short u16x4;
typedef unsigned short u16;

#define MFMA(a, b, c) __builtin_amdgcn_mfma_f32_16x16x32_bf16((a), (b), (c), 0, 0, 0)

__device__ __forceinline__ u16 f2bf(float x) {
    __hip_bfloat16 h = __float2bfloat16(x);            // RTN
    return __builtin_bit_cast(u16, h);
}
__device__ __forceinline__ float bf2f(u16 u) {
    unsigned v = ((unsigned)u) << 16;
    return __builtin_bit_cast(float, v);
}

// DPP lane exchange within 16-lane rows (VALU-speed, no LDS pipe).
template <int CTRL>
__device__ __forceinline__ float dpp_f(float v) {
    return __builtin_bit_cast(float, __builtin_amdgcn_mov_dpp(
        __builtin_bit_cast(int, v), CTRL, 0xf, 0xf, false));
}
// full 16-lane max/sum: quad_perm[1,0,3,2]=0xB1, quad_perm[2,3,0,1]=0x4E,
// row_half_mirror=0x141, row_mirror=0x140
__device__ __forceinline__ float red16_max(float v) {
    v = fmaxf(v, dpp_f<0xB1>(v));
    v = fmaxf(v, dpp_f<0x4E>(v));
    v = fmaxf(v, dpp_f<0x141>(v));
    v = fmaxf(v, dpp_f<0x140>(v));
    return v;
}
__device__ __forceinline__ float red16_sum(float v) {
    v += dpp_f<0xB1>(v);
    v += dpp_f<0x4E>(v);
    v += dpp_f<0x141>(v);
    v += dpp_f<0x140>(v);
    return v;
}

// ---------------------------------------------------------------------------
// Tiled fp32 GEMM: C = A(MxK) * B(KxN), row-major. Batched via grid.z.
// mode 0: fp32 C.  mode 1: bf16 hi/lo planes, row-major [M][N], pre-scaled.
// mode 2: bf16 hi/lo planes TRANSPOSED [N][M] (for V^T), pre-scaled.
// ---------------------------------------------------------------------------
__global__ __launch_bounds__(256) void gemm_tiled_f32(
    const float* __restrict__ A, const float* __restrict__ Bw,
    float* __restrict__ C, u16* __restrict__ Chi, u16* __restrict__ Clo,
    int M, int N, int K, int hdiv, long aStride, long bStride, long cStride,
    int mode, float scale)
{
    __shared__ float As[32][68];  // [k][m]
    __shared__ float Bs[32][68];  // [k][n]

    const int z = blockIdx.z;
    A  += (long)(z / hdiv) * aStride;
    Bw += (long)(z % hdiv) * bStride;
    if (mode == 0) C += (long)z * cStride;
    else { Chi += (long)z * cStride; Clo += (long)z * cStride; }

    const int m0 = blockIdx.x * 64;
    const int n0 = blockIdx.y * 64;
    const int t  = threadIdx.x;
    const int tx = t & 15;
    const int ty = t >> 4;

    float acc[4][4] = {{0.f}};

    for (int k0 = 0; k0 < K; k0 += 32) {
        #pragma unroll
        for (int i = 0; i < 2; ++i) {
            int idx = t + i * 256;
            int r   = idx >> 3;
            int c4  = idx & 7;
            const float4 v = *(const float4*)(A + (long)(m0 + r) * K + k0 + c4 * 4);
            As[c4 * 4 + 0][r] = v.x;
            As[c4 * 4 + 1][r] = v.y;
            As[c4 * 4 + 2][r] = v.z;
            As[c4 * 4 + 3][r] = v.w;
        }
        #pragma unroll
        for (int i = 0; i < 2; ++i) {
            int idx = t + i * 256;
            int r   = idx >> 4;
            int c4  = idx & 15;
            *(float4*)&Bs[r][c4 * 4] = *(const float4*)(Bw + (long)(k0 + r) * N + n0 + c4 * 4);
        }
        __syncthreads();

        #pragma unroll
        for (int kk = 0; kk < 32; ++kk) {
            const float4 av = *(const float4*)&As[kk][ty * 4];
            const float4 bv = *(const float4*)&Bs[kk][tx * 4];
            const float a4[4] = {av.x, av.y, av.z, av.w};
            const float b4[4] = {bv.x, bv.y, bv.z, bv.w};
            #pragma unroll
            for (int i = 0; i < 4; ++i)
                #pragma unroll
                for (int j = 0; j < 4; ++j)
                    acc[i][j] = fmaf(a4[i], b4[j], acc[i][j]);
        }
        __syncthreads();
    }

    if (mode == 0) {
        #pragma unroll
        for (int i = 0; i < 4; ++i) {
            float4 v = make_float4(acc[i][0], acc[i][1], acc[i][2], acc[i][3]);
            *(float4*)(C + (long)(m0 + ty * 4 + i) * N + n0 + tx * 4) = v;
        }
    } else if (mode == 1) {
        #pragma unroll
        for (int i = 0; i < 4; ++i) {
            const int row = m0 + ty * 4 + i;
            u16x4 hv, lv;
            #pragma unroll
            for (int c = 0; c < 4; ++c) {
                const float x = acc[i][c] * scale;
                const u16 hu = f2bf(x);
                hv[c] = hu;
                lv[c] = f2bf(x - bf2f(hu));
            }
            *(u16x4*)(Chi + (size_t)row * N + n0 + tx * 4) = hv;
            *(u16x4*)(Clo + (size_t)row * N + n0 + tx * 4) = lv;
        }
    } else { // mode 2: transposed [N][M], M == SEQ here
        #pragma unroll
        for (int i = 0; i < 4; ++i) {
            const int row = m0 + ty * 4 + i;
            #pragma unroll
            for (int c = 0; c < 4; ++c) {
                const int col = n0 + tx * 4 + c;
                const float x = acc[i][c] * scale;
                const u16 hu = f2bf(x);
                Chi[(size_t)col * M + row] = hu;
                Clo[(size_t)col * M + row] = f2bf(x - bf2f(hu));
            }
        }
    }
}

// ---------------------------------------------------------------------------
// MFMA flash attention v2. Block = 256 threads = 4 waves; wave = 16 q-rows.
// Load-balance: grid.x = 16 pairs; block handles q-tile pair (i, 31-i) so
// every block does ~66 uniform k-steps (kills the causal drain tail).
// Per 32-key step: QK^T hi/lo as 4 independent 3-deep MFMA chains, row-max
// via DPP (no ds-pipe shuffles), defer-rescale (__any guard, exact),
// P->bf16 LDS bounce, PV with V^T hi/lo. Q pre-scaled by 8.
// ---------------------------------------------------------------------------
__global__ __launch_bounds__(256) void flash_mfma(
    const u16* __restrict__ Qhi, const u16* __restrict__ Qlo,
    const u16* __restrict__ Khi, const u16* __restrict__ Klo,
    const u16* __restrict__ VThi, const u16* __restrict__ VTlo,
    float* __restrict__ Om, const int* __restrict__ maskp)
{
    const int t   = threadIdx.x;
    const int wv  = t >> 6;
    const int l   = t & 63;
    const int g   = l >> 4;     // lane group 0..3
    const int m16 = l & 15;
    const int h = blockIdx.y, b = blockIdx.z;
    const int msk = maskp[0];

    const size_t bh = (size_t)b * NH + h;
    const u16* __restrict__ Qh = Qhi + bh * SEQ * DKS;
    const u16* __restrict__ Ql = Qlo + bh * SEQ * DKS;
    const u16* __restrict__ Kh = Khi + bh * SEQ * DKS;
    const u16* __restrict__ Kl = Klo + bh * SEQ * DKS;
    const u16* __restrict__ Vh = VThi + bh * DKS * SEQ;
    const u16* __restrict__ Vl = VTlo + bh * DKS * SEQ;

    __shared__ u16 P_lds[4][16][32];

    for (int half = 0; half < 2; ++half) {
        const int tile = half ? (31 - (int)blockIdx.x) : (int)blockIdx.x;
        const int q0   = tile * 64 + wv * 16;

        // Q fragments for this tile
        const size_t qoff = (size_t)(q0 + m16) * DKS + 8 * g;
        const short8v qh0 = *(const short8v*)(Qh + qoff);
        const short8v qh1 = *(const short8v*)(Qh + qoff + 32);
        const short8v ql0 = *(const short8v*)(Ql + qoff);
        const short8v ql1 = *(const short8v*)(Ql + qoff + 32);

        f32x4 o0 = {0.f, 0.f, 0.f, 0.f}, o1 = o0, o2 = o0, o3 = o0;
        float mr[4] = {-INFINITY, -INFINITY, -INFINITY, -INFINITY};
        float lr[4] = {0.f, 0.f, 0.f, 0.f};

        const int qrow_base = q0 + 4 * g;          // this lane's C rows: +0..3
        const int ncol = msk ? (q0 + 16) : SEQ;

        for (int k0 = 0; k0 < ncol; k0 += 32) {
            // ---- load all K fragments for both 16-key subtiles ----
            const size_t koA = (size_t)(k0 + m16) * DKS + 8 * g;
            const size_t koB = (size_t)(k0 + 16 + m16) * DKS + 8 * g;
            const short8v akh0 = *(const short8v*)(Kh + koA);
            const short8v akh1 = *(const short8v*)(Kh + koA + 32);
            const short8v akl0 = *(const short8v*)(Kl + koA);
            const short8v akl1 = *(const short8v*)(Kl + koA + 32);
            const short8v bkh0 = *(const short8v*)(Kh + koB);
            const short8v bkh1 = *(const short8v*)(Kh + koB + 32);
            const short8v bkl0 = *(const short8v*)(Kl + koB);
            const short8v bkl1 = *(const short8v*)(Kl + koB + 32);

            // ---- QK^T: 4 independent 3-deep chains ----
            f32x4 s0a = {0.f, 0.f, 0.f, 0.f}, s0b = s0a, s1a = s0a, s1b = s0a;
            __builtin_amdgcn_s_setprio(1);
            s0a = MFMA(qh0, akh0, s0a); s0b = MFMA(ql0, akh0, s0b);
            s1a = MFMA(qh0, bkh0, s1a); s1b = MFMA(ql0, bkh0, s1b);
            s0a = MFMA(qh1, akh1, s0a); s0b = MFMA(ql1, akh1, s0b);
            s1a = MFMA(qh1, bkh1, s1a); s1b = MFMA(ql1, bkh1, s1b);
            s0a = MFMA(qh0, akl0, s0a); s0b = MFMA(qh1, akl1, s0b);
            s1a = MFMA(qh0, bkl0, s1a); s1b = MFMA(qh1, bkl1, s1b);
            __builtin_amdgcn_s_setprio(0);
            f32x4 s0 = s0a + s0b;
            f32x4 s1 = s1a + s1b;

            if (msk && (k0 + 31 > q0)) {           // diagonal-straddling tiles only
                #pragma unroll
                for (int r = 0; r < 4; ++r) {
                    if (k0 + m16      > qrow_base + r) s0[r] = -INFINITY;
                    if (k0 + 16 + m16 > qrow_base + r) s1[r] = -INFINITY;
                }
            }

            // ---- row max via DPP, defer-rescale ----
            float nm[4];
            int grew = 0;
            #pragma unroll
            for (int r = 0; r < 4; ++r) {
                const float v = red16_max(fmaxf(s0[r], s1[r]));
                nm[r] = fmaxf(mr[r], v);
                grew |= (nm[r] > mr[r]);
            }
            if (__any(grew)) {
                #pragma unroll
                for (int r = 0; r < 4; ++r) {
                    const float al = __expf(mr[r] - nm[r]);  // first tile: exp(-inf)=0
                    mr[r] = nm[r];
                    lr[r] *= al;
                    o0[r] *= al; o1[r] *= al; o2[r] *= al; o3[r] *= al;
                }
            }

            #pragma unroll
            for (int r = 0; r < 4; ++r) {
                const u16 up0 = f2bf(__expf(s0[r] - mr[r]));
                const u16 up1 = f2bf(__expf(s1[r] - mr[r]));
                lr[r] += bf2f(up0) + bf2f(up1);      // denom matches bf16 P
                P_lds[wv][4 * g + r][m16]      = up0;
                P_lds[wv][4 * g + r][16 + m16] = up1;
            }

            // A-fragment of P (intra-wave LDS bounce, no barrier needed)
            const short8v pa = *(const short8v*)&P_lds[wv][m16][8 * g];

            // ---- PV: O += P * (Vhi + Vlo) ----
            const size_t vo = (size_t)m16 * SEQ + k0 + 8 * g;
            const short8v vh0 = *(const short8v*)(Vh + vo);
            const short8v vl0 = *(const short8v*)(Vl + vo);
            const short8v vh1 = *(const short8v*)(Vh + vo + 16 * SEQ);
            const short8v vl1 = *(const short8v*)(Vl + vo + 16 * SEQ);
            const short8v vh2 = *(const short8v*)(Vh + vo + 32 * SEQ);
            const short8v vl2 = *(const short8v*)(Vl + vo + 32 * SEQ);
            const short8v vh3 = *(const short8v*)(Vh + vo + 48 * SEQ);
            const short8v vl3 = *(const short8v*)(Vl + vo + 48 * SEQ);
            __builtin_amdgcn_s_setprio(1);
            o0 = MFMA(pa, vh0, o0); o1 = MFMA(pa, vh1, o1);
            o2 = MFMA(pa, vh2, o2); o3 = MFMA(pa, vh3, o3);
            o0 = MFMA(pa, vl0, o0); o1 = MFMA(pa, vl1, o1);
            o2 = MFMA(pa, vl2, o2); o3 = MFMA(pa, vl3, o3);
            __builtin_amdgcn_s_setprio(0);
        }

        float inv[4];
        #pragma unroll
        for (int r = 0; r < 4; ++r) inv[r] = 1.0f / red16_sum(lr[r]);

        #pragma unroll
        for (int r = 0; r < 4; ++r) {
            const size_t obase = ((size_t)b * SEQ + qrow_base + r) * EMB + h * DKS + m16;
            Om[obase +  0] = o0[r] * inv[r];
            Om[obase + 16] = o1[r] * inv[r];
            Om[obase + 32] = o2[r] * inv[r];
            Om[obase + 48] = o3[r] * inv[r];
        }
    }
}

// ---------------------------------------------------------------------------
extern "C" void kernel_launch(void* const* d_in, const int* in_sizes, int n_in,
                              void* d_out, int out_size, void* d_ws, size_t ws_size,
                              hipStream_t stream)
{
    const float* x_q = (const float*)d_in[0];
    const float* x_k = (const float*)d_in[1];
    const float* x_v = (const float*)d_in[2];
    const float* w_q = (const float*)d_in[3];
    const float* w_k = (const float*)d_in[4];
    const float* w_v = (const float*)d_in[5];
    const float* w_o = (const float*)d_in[6];
    const int*  maskp = (const int*)d_in[7];
    float* out = (float*)d_out;

    // workspace: 6 bf16 planes (Qhi,Qlo,Khi,Klo,VThi,VTlo; 16 MB each) + attn fp32 (32 MB) = 128 MB
    const size_t PLANE = (size_t)BATCH * NH * SEQ * DKS;   // 8M elements
    u16* Qhi  = (u16*)d_ws;
    u16* Qlo  = Qhi + PLANE;
    u16* Khi  = Qhi + 2 * PLANE;
    u16* Klo  = Qhi + 3 * PLANE;
    u16* VThi = Qhi + 4 * PLANE;
    u16* VTlo = Qhi + 5 * PLANE;
    float* attn = (float*)(Qhi + 6 * PLANE);               // [B][S][H*DK]

    const dim3 blk(256);

    // projections -> bf16 hi/lo planes; Q pre-scaled by 8 (score scale)
    const dim3 gp(SEQ / 64, DKS / 64, BATCH * NH);
    gemm_tiled_f32<<<gp, blk, 0, stream>>>(x_q, w_q, nullptr, Qhi, Qlo, SEQ, DKS, EMB, NH,
        (long)SEQ * EMB, (long)EMB * DKS, (long)SEQ * DKS, 1, 8.0f);
    gemm_tiled_f32<<<gp, blk, 0, stream>>>(x_k, w_k, nullptr, Khi, Klo, SEQ, DKS, EMB, NH,
        (long)SEQ * EMB, (long)EMB * DKS, (long)SEQ * DKS, 1, 1.0f);
    gemm_tiled_f32<<<gp, blk, 0, stream>>>(x_v, w_v, nullptr, VThi, VTlo, SEQ, DKS, EMB, NH,
        (long)SEQ * EMB, (long)EMB * DKS, (long)DKS * SEQ, 2, 1.0f);

    // attention: 16 tile-pairs per (b,h) for uniform per-block work
    const dim3 gf(SEQ / 128, NH, BATCH);
    flash_mfma<<<gf, blk, 0, stream>>>(Qhi, Qlo, Khi, Klo, VThi, VTlo, attn, maskp);

    // output projection (fp32)
    const dim3 go((BATCH * SEQ) / 64, EMB / 64, 1);
    gemm_tiled_f32<<<go, blk, 0, stream>>>(attn, w_o, out, nullptr, nullptr,
        BATCH * SEQ, EMB, EMB, 1, 0L, 0L, 0L, 0, 1.0f);
}

// Round 11
// 1048.442 us; speedup vs baseline: 3.8096x; 1.3976x over previous
//
#include <hip/hip_runtime.h>
#include <hip/hip_bf16.h>
#include <math.h>

#define BATCH 4
#define SEQ   2048
#define EMB   1024
#define NH    16
#define DKS   64

typedef __attribute__((ext_vector_type(8))) short short8v;   // 8 bf16 (4 VGPRs)
typedef __attribute__((ext_vector_type(4))) float f32x4;
typedef unsigned short u16;
typedef unsigned int   u32;

#define MFMA(a, b, c) __builtin_amdgcn_mfma_f32_16x16x32_bf16((a), (b), (c), 0, 0, 0)

__device__ __forceinline__ u16 f2bf(float x) {
    __hip_bfloat16 h = __float2bfloat16(x);            // RTN
    return __builtin_bit_cast(u16, h);
}
__device__ __forceinline__ float bf2f(u16 u) {
    unsigned v = ((unsigned)u) << 16;
    return __builtin_bit_cast(float, v);
}

// DPP lane exchange within 16-lane rows (VALU-speed, no LDS pipe).
template <int CTRL>
__device__ __forceinline__ float dpp_f(float v) {
    return __builtin_bit_cast(float, __builtin_amdgcn_mov_dpp(
        __builtin_bit_cast(int, v), CTRL, 0xf, 0xf, false));
}
__device__ __forceinline__ float red16_max(float v) {
    v = fmaxf(v, dpp_f<0xB1>(v));
    v = fmaxf(v, dpp_f<0x4E>(v));
    v = fmaxf(v, dpp_f<0x141>(v));
    v = fmaxf(v, dpp_f<0x140>(v));
    return v;
}
__device__ __forceinline__ float red16_sum(float v) {
    v += dpp_f<0xB1>(v);
    v += dpp_f<0x4E>(v);
    v += dpp_f<0x141>(v);
    v += dpp_f<0x140>(v);
    return v;
}

// ---------------------------------------------------------------------------
// MFMA GEMM with on-the-fly fp32 -> bf16 hi/lo split in LDS staging.
// C = A(MxK) * B(KxN) row-major, batched via grid.z (A += z/hdiv*aStride, ...).
// Tile 128x64, BK=32, 256 thr (4 waves, each wave 32 rows x 64 cols).
// One staged BK=32 tile = ONE K=32 MFMA per frag pair (lane k = 8*(l>>4)+0..7),
// 3 MFMAs per (rt,ct) for hi/lo (ah*bh + al*bh + ah*bl); lo*lo dropped (~2^-16).
// LDS rows padded to 40 u16 (80 B); max in-row frag offset 24+8=32 <= 40.
// mode 0: fp32 C. mode 1: bf16 hi/lo planes [M][N]. mode 2: transposed [N][M].
// ---------------------------------------------------------------------------
__global__ __launch_bounds__(256) void gemm_mfma(
    const float* __restrict__ A, const float* __restrict__ Bw,
    float* __restrict__ Cf, u16* __restrict__ Chi, u16* __restrict__ Clo,
    int M, int N, int K, int hdiv, long aStride, long bStride, long cStride,
    int mode, float scale)
{
    __shared__ u16 Ah[128 * 40];
    __shared__ u16 Al[128 * 40];
    __shared__ u16 Bh[64 * 40];
    __shared__ u16 Bl[64 * 40];

    const int z = blockIdx.z;
    A  += (size_t)(z / hdiv) * aStride;
    Bw += (size_t)(z % hdiv) * bStride;
    if (mode == 0) Cf += (size_t)z * cStride;
    else { Chi += (size_t)z * cStride; Clo += (size_t)z * cStride; }

    const int m0  = blockIdx.x * 128;
    const int n0  = blockIdx.y * 64;
    const int t   = threadIdx.x;
    const int wv  = t >> 6;
    const int l   = t & 63;
    const int g   = l >> 4;
    const int m16 = l & 15;
    const int wr  = wv * 32;

    f32x4 acc[2][4];
    #pragma unroll
    for (int rt = 0; rt < 2; ++rt)
        #pragma unroll
        for (int ct = 0; ct < 4; ++ct) acc[rt][ct] = f32x4{0.f, 0.f, 0.f, 0.f};

    for (int k0 = 0; k0 < K; k0 += 32) {
        // ---- stage A tile (128 x 32 fp32 -> hi/lo bf16), row-major [row][k] ----
        #pragma unroll
        for (int j = 0; j < 4; ++j) {
            const int idx = t + j * 256;           // 0..1023 float4s
            const int r   = idx >> 3;              // row 0..127
            const int c4  = idx & 7;               // k-group
            const float4 v = *(const float4*)(A + (size_t)(m0 + r) * K + k0 + 4 * c4);
            const u16 h0 = f2bf(v.x), h1 = f2bf(v.y), h2 = f2bf(v.z), h3 = f2bf(v.w);
            const u16 e0 = f2bf(v.x - bf2f(h0)), e1 = f2bf(v.y - bf2f(h1));
            const u16 e2 = f2bf(v.z - bf2f(h2)), e3 = f2bf(v.w - bf2f(h3));
            const int o = r * 40 + 4 * c4;
            *(u32*)&Ah[o]     = (u32)h0 | ((u32)h1 << 16);
            *(u32*)&Ah[o + 2] = (u32)h2 | ((u32)h3 << 16);
            *(u32*)&Al[o]     = (u32)e0 | ((u32)e1 << 16);
            *(u32*)&Al[o + 2] = (u32)e2 | ((u32)e3 << 16);
        }
        // ---- stage B tile (32 x 64 fp32 -> hi/lo bf16), TRANSPOSED [col][k] ----
        #pragma unroll
        for (int j = 0; j < 2; ++j) {
            const int idx = t + j * 256;           // 0..511 float4s
            const int kr  = idx >> 4;              // k row 0..31
            const int c4  = idx & 15;              // col group
            const float4 v = *(const float4*)(Bw + (size_t)(k0 + kr) * N + n0 + 4 * c4);
            const u16 h0 = f2bf(v.x), h1 = f2bf(v.y), h2 = f2bf(v.z), h3 = f2bf(v.w);
            Bh[(4 * c4 + 0) * 40 + kr] = h0;
            Bh[(4 * c4 + 1) * 40 + kr] = h1;
            Bh[(4 * c4 + 2) * 40 + kr] = h2;
            Bh[(4 * c4 + 3) * 40 + kr] = h3;
            Bl[(4 * c4 + 0) * 40 + kr] = f2bf(v.x - bf2f(h0));
            Bl[(4 * c4 + 1) * 40 + kr] = f2bf(v.y - bf2f(h1));
            Bl[(4 * c4 + 2) * 40 + kr] = f2bf(v.z - bf2f(h2));
            Bl[(4 * c4 + 3) * 40 + kr] = f2bf(v.w - bf2f(h3));
        }
        __syncthreads();

        // ---- one K=32 step: 12 ds_read_b128 + 24 MFMAs ----
        short8v a_h[2], a_l[2], b_h[4], b_l[4];
        #pragma unroll
        for (int rt = 0; rt < 2; ++rt) {
            const int o = (wr + 16 * rt + m16) * 40 + 8 * g;
            a_h[rt] = *(const short8v*)&Ah[o];
            a_l[rt] = *(const short8v*)&Al[o];
        }
        #pragma unroll
        for (int ct = 0; ct < 4; ++ct) {
            const int o = (16 * ct + m16) * 40 + 8 * g;
            b_h[ct] = *(const short8v*)&Bh[o];
            b_l[ct] = *(const short8v*)&Bl[o];
        }
        __builtin_amdgcn_s_setprio(1);
        #pragma unroll
        for (int rt = 0; rt < 2; ++rt)
            #pragma unroll
            for (int ct = 0; ct < 4; ++ct) {
                acc[rt][ct] = MFMA(a_h[rt], b_h[ct], acc[rt][ct]);
                acc[rt][ct] = MFMA(a_l[rt], b_h[ct], acc[rt][ct]);
                acc[rt][ct] = MFMA(a_h[rt], b_l[ct], acc[rt][ct]);
            }
        __builtin_amdgcn_s_setprio(0);
        __syncthreads();
    }

    // ---- epilogue: C row = A-index (4g+r within tile), col = B-index (m16) ----
    #pragma unroll
    for (int rt = 0; rt < 2; ++rt)
        #pragma unroll
        for (int ct = 0; ct < 4; ++ct)
            #pragma unroll
            for (int r = 0; r < 4; ++r) {
                const size_t row = (size_t)(m0 + wr + 16 * rt + 4 * g + r);
                const int    col = n0 + 16 * ct + m16;
                const float  x   = acc[rt][ct][r] * scale;
                if (mode == 0) {
                    Cf[row * N + col] = x;
                } else if (mode == 1) {
                    const u16 hu = f2bf(x);
                    Chi[row * N + col] = hu;
                    Clo[row * N + col] = f2bf(x - bf2f(hu));
                } else {  // mode 2: [N][M] transposed (V^T), M == SEQ
                    const u16 hu = f2bf(x);
                    Chi[(size_t)col * M + row] = hu;
                    Clo[(size_t)col * M + row] = f2bf(x - bf2f(hu));
                }
            }
}

// ---------------------------------------------------------------------------
// MFMA flash attention v3. Pairing, DPP reduce, defer-rescale; 1-D grid with
// XCD-aware decode: the 16 pair-blocks of each (b,h) share bid%8 -> same XCD
// -> K/V planes served from that XCD's L2.
// ---------------------------------------------------------------------------
__global__ __launch_bounds__(256) void flash_mfma(
    const u16* __restrict__ Qhi, const u16* __restrict__ Qlo,
    const u16* __restrict__ Khi, const u16* __restrict__ Klo,
    const u16* __restrict__ VThi, const u16* __restrict__ VTlo,
    float* __restrict__ Om, const int* __restrict__ maskp)
{
    const int t   = threadIdx.x;
    const int wv  = t >> 6;
    const int l   = t & 63;
    const int g   = l >> 4;
    const int m16 = l & 15;
    const int msk = maskp[0];

    // XCD decode: bid = (pair + (bh>>3)*16)*8 + (bh&7)
    const int bid     = blockIdx.x;
    const int slot    = bid & 7;
    const int jj      = bid >> 3;
    const int pairIdx = jj & 15;
    const int bh_     = ((jj >> 4) << 3) | slot;    // 0..63
    const int b       = bh_ >> 4;
    const int h       = bh_ & 15;

    const size_t bh = (size_t)b * NH + h;
    const u16* __restrict__ Qh = Qhi + bh * SEQ * DKS;
    const u16* __restrict__ Ql = Qlo + bh * SEQ * DKS;
    const u16* __restrict__ Kh = Khi + bh * SEQ * DKS;
    const u16* __restrict__ Kl = Klo + bh * SEQ * DKS;
    const u16* __restrict__ Vh = VThi + bh * DKS * SEQ;
    const u16* __restrict__ Vl = VTlo + bh * DKS * SEQ;

    __shared__ u16 P_lds[4][16][32];

    for (int half = 0; half < 2; ++half) {
        const int tile = half ? (31 - pairIdx) : pairIdx;
        const int q0   = tile * 64 + wv * 16;

        const size_t qoff = (size_t)(q0 + m16) * DKS + 8 * g;
        const short8v qh0 = *(const short8v*)(Qh + qoff);
        const short8v qh1 = *(const short8v*)(Qh + qoff + 32);
        const short8v ql0 = *(const short8v*)(Ql + qoff);
        const short8v ql1 = *(const short8v*)(Ql + qoff + 32);

        f32x4 o0 = {0.f, 0.f, 0.f, 0.f}, o1 = o0, o2 = o0, o3 = o0;
        float mr[4] = {-INFINITY, -INFINITY, -INFINITY, -INFINITY};
        float lr[4] = {0.f, 0.f, 0.f, 0.f};

        const int qrow_base = q0 + 4 * g;
        const int ncol = msk ? (q0 + 16) : SEQ;

        for (int k0 = 0; k0 < ncol; k0 += 32) {
            const size_t koA = (size_t)(k0 + m16) * DKS + 8 * g;
            const size_t koB = (size_t)(k0 + 16 + m16) * DKS + 8 * g;
            const short8v akh0 = *(const short8v*)(Kh + koA);
            const short8v akh1 = *(const short8v*)(Kh + koA + 32);
            const short8v akl0 = *(const short8v*)(Kl + koA);
            const short8v akl1 = *(const short8v*)(Kl + koA + 32);
            const short8v bkh0 = *(const short8v*)(Kh + koB);
            const short8v bkh1 = *(const short8v*)(Kh + koB + 32);
            const short8v bkl0 = *(const short8v*)(Kl + koB);
            const short8v bkl1 = *(const short8v*)(Kl + koB + 32);

            f32x4 s0a = {0.f, 0.f, 0.f, 0.f}, s0b = s0a, s1a = s0a, s1b = s0a;
            __builtin_amdgcn_s_setprio(1);
            s0a = MFMA(qh0, akh0, s0a); s0b = MFMA(ql0, akh0, s0b);
            s1a = MFMA(qh0, bkh0, s1a); s1b = MFMA(ql0, bkh0, s1b);
            s0a = MFMA(qh1, akh1, s0a); s0b = MFMA(ql1, akh1, s0b);
            s1a = MFMA(qh1, bkh1, s1a); s1b = MFMA(ql1, bkh1, s1b);
            s0a = MFMA(qh0, akl0, s0a); s0b = MFMA(qh1, akl1, s0b);
            s1a = MFMA(qh0, bkl0, s1a); s1b = MFMA(qh1, bkl1, s1b);
            __builtin_amdgcn_s_setprio(0);
            f32x4 s0 = s0a + s0b;
            f32x4 s1 = s1a + s1b;

            if (msk && (k0 + 31 > q0)) {
                #pragma unroll
                for (int r = 0; r < 4; ++r) {
                    if (k0 + m16      > qrow_base + r) s0[r] = -INFINITY;
                    if (k0 + 16 + m16 > qrow_base + r) s1[r] = -INFINITY;
                }
            }

            float nm[4];
            int grew = 0;
            #pragma unroll
            for (int r = 0; r < 4; ++r) {
                const float v = red16_max(fmaxf(s0[r], s1[r]));
                nm[r] = fmaxf(mr[r], v);
                grew |= (nm[r] > mr[r]);
            }
            if (__any(grew)) {
                #pragma unroll
                for (int r = 0; r < 4; ++r) {
                    const float al = __expf(mr[r] - nm[r]);
                    mr[r] = nm[r];
                    lr[r] *= al;
                    o0[r] *= al; o1[r] *= al; o2[r] *= al; o3[r] *= al;
                }
            }

            #pragma unroll
            for (int r = 0; r < 4; ++r) {
                const u16 up0 = f2bf(__expf(s0[r] - mr[r]));
                const u16 up1 = f2bf(__expf(s1[r] - mr[r]));
                lr[r] += bf2f(up0) + bf2f(up1);
                P_lds[wv][4 * g + r][m16]      = up0;
                P_lds[wv][4 * g + r][16 + m16] = up1;
            }

            const short8v pa = *(const short8v*)&P_lds[wv][m16][8 * g];

            const size_t vo = (size_t)m16 * SEQ + k0 + 8 * g;
            const short8v vh0 = *(const short8v*)(Vh + vo);
            const short8v vl0 = *(const short8v*)(Vl + vo);
            const short8v vh1 = *(const short8v*)(Vh + vo + 16 * SEQ);
            const short8v vl1 = *(const short8v*)(Vl + vo + 16 * SEQ);
            const short8v vh2 = *(const short8v*)(Vh + vo + 32 * SEQ);
            const short8v vl2 = *(const short8v*)(Vl + vo + 32 * SEQ);
            const short8v vh3 = *(const short8v*)(Vh + vo + 48 * SEQ);
            const short8v vl3 = *(const short8v*)(Vl + vo + 48 * SEQ);
            __builtin_amdgcn_s_setprio(1);
            o0 = MFMA(pa, vh0, o0); o1 = MFMA(pa, vh1, o1);
            o2 = MFMA(pa, vh2, o2); o3 = MFMA(pa, vh3, o3);
            o0 = MFMA(pa, vl0, o0); o1 = MFMA(pa, vl1, o1);
            o2 = MFMA(pa, vl2, o2); o3 = MFMA(pa, vl3, o3);
            __builtin_amdgcn_s_setprio(0);
        }

        float inv[4];
        #pragma unroll
        for (int r = 0; r < 4; ++r) inv[r] = 1.0f / red16_sum(lr[r]);

        #pragma unroll
        for (int r = 0; r < 4; ++r) {
            const size_t obase = ((size_t)b * SEQ + qrow_base + r) * EMB + h * DKS + m16;
            Om[obase +  0] = o0[r] * inv[r];
            Om[obase + 16] = o1[r] * inv[r];
            Om[obase + 32] = o2[r] * inv[r];
            Om[obase + 48] = o3[r] * inv[r];
        }
    }
}

// ---------------------------------------------------------------------------
extern "C" void kernel_launch(void* const* d_in, const int* in_sizes, int n_in,
                              void* d_out, int out_size, void* d_ws, size_t ws_size,
                              hipStream_t stream)
{
    const float* x_q = (const float*)d_in[0];
    const float* x_k = (const float*)d_in[1];
    const float* x_v = (const float*)d_in[2];
    const float* w_q = (const float*)d_in[3];
    const float* w_k = (const float*)d_in[4];
    const float* w_v = (const float*)d_in[5];
    const float* w_o = (const float*)d_in[6];
    const int*  maskp = (const int*)d_in[7];
    float* out = (float*)d_out;

    // workspace: 6 bf16 planes (16 MB each) + attn fp32 (32 MB) = 128 MB
    const size_t PLANE = (size_t)BATCH * NH * SEQ * DKS;   // 8M elements
    u16* Qhi  = (u16*)d_ws;
    u16* Qlo  = Qhi + PLANE;
    u16* Khi  = Qhi + 2 * PLANE;
    u16* Klo  = Qhi + 3 * PLANE;
    u16* VThi = Qhi + 4 * PLANE;
    u16* VTlo = Qhi + 5 * PLANE;
    float* attn = (float*)(Qhi + 6 * PLANE);               // [B][S][H*DK]

    const dim3 blk(256);

    // projections (MFMA, on-the-fly hi/lo): per (b,h) x[b](SxE) * w[h](ExDK)
    const dim3 gp(SEQ / 128, 1, BATCH * NH);
    gemm_mfma<<<gp, blk, 0, stream>>>(x_q, w_q, nullptr, Qhi, Qlo, SEQ, DKS, EMB, NH,
        (long)SEQ * EMB, (long)EMB * DKS, (long)SEQ * DKS, 1, 8.0f);
    gemm_mfma<<<gp, blk, 0, stream>>>(x_k, w_k, nullptr, Khi, Klo, SEQ, DKS, EMB, NH,
        (long)SEQ * EMB, (long)EMB * DKS, (long)SEQ * DKS, 1, 1.0f);
    gemm_mfma<<<gp, blk, 0, stream>>>(x_v, w_v, nullptr, VThi, VTlo, SEQ, DKS, EMB, NH,
        (long)SEQ * EMB, (long)EMB * DKS, (long)DKS * SEQ, 2, 1.0f);

    // attention: flat 1024-block grid, XCD-aware decode inside
    flash_mfma<<<dim3(1024), blk, 0, stream>>>(Qhi, Qlo, Khi, Klo, VThi, VTlo, attn, maskp);

    // output projection (MFMA, fp32 out): attn(B*S x E) * w_o(E x E)
    const dim3 go((BATCH * SEQ) / 128, EMB / 64, 1);
    gemm_mfma<<<go, blk, 0, stream>>>(attn, w_o, out, nullptr, nullptr,
        BATCH * SEQ, EMB, EMB, 1, 0L, 0L, 0L, 0, 1.0f);
}